// Round 4
// baseline (504.591 us; speedup 1.0000x reference)
//
#include <hip/hip_runtime.h>

// ResidualNetwork forward, fp32, MI355X (gfx950).
// Round 4: weights prepacked (duplicated (w,w) float2 pairs, exact use order)
// -> staged into LDS per workgroup -> all 64 lanes ds_read the SAME address
// (bank broadcast, no conflict). Weight delivery moves to the DS pipe,
// co-scheduled with VALU (m114); bias ds_reads land directly in accumulator
// VGPR pairs (no v_mov init). ds_read_b128 fetches 2 weight-pairs per op.
// VALU stream is ~pure v_pk_fma_f32 (half-rate, 4cyc) + v_pk_max_f32.
// Stream layout (float2 entries):
//   [0,40)      layer0 per j: b0[j], w0[0][j], w0[1][j], w0[2][j]
//   [40,150)    layer1: b1[10], w1[100] (k-major)
//   [150,3350)  10 blocks x 320: B1[10], W1[100], (B2+B3)[10], W2[100], W3[100]
//   [3350,3460) layer8: b8[10], w8[100]
//   [3460,3472) out: b9, pad, w9[10]

#define NPTS 4194304
#define H 10
#define L 10

#define L1_OFF 40
#define BLK_OFF 150
#define BLK_STRIDE 320
#define L8_OFF 3350
#define L9_OFF 3460
#define NENT 3472

typedef float v2f __attribute__((ext_vector_type(2)));
typedef float v4f __attribute__((ext_vector_type(4)));

__device__ __forceinline__ v2f tov2(float2 w) { v2f r; r.x = w.x; r.y = w.y; return r; }
__device__ __forceinline__ v2f bc(float s) { v2f r; r.x = s; r.y = s; return r; }
__device__ __forceinline__ v2f fma2v(v2f a, v2f w, v2f c) {
    return __builtin_elementwise_fma(a, w, c);
}
__device__ __forceinline__ v2f relu2(v2f a) {
    return __builtin_elementwise_max(a, bc(0.0f));
}

// ---------------- prepack: scatter weights into use-order duplicated pairs ----
__global__ __launch_bounds__(256) void prepack(
    const float* __restrict__ w0, const float* __restrict__ b0,
    const float* __restrict__ w1, const float* __restrict__ b1,
    const float* __restrict__ Wr1, const float* __restrict__ Br1,
    const float* __restrict__ Wr2, const float* __restrict__ Br2,
    const float* __restrict__ Wr3, const float* __restrict__ Br3,
    const float* __restrict__ w8, const float* __restrict__ b8,
    const float* __restrict__ w9, const float* __restrict__ b9,
    float2* __restrict__ wp)
{
    for (int idx = threadIdx.x; idx < NENT; idx += 256) {
        float v;
        if (idx < L1_OFF) {                       // layer0 interleaved
            int j = idx >> 2, r = idx & 3;
            v = (r == 0) ? b0[j] : w0[(r - 1) * H + j];
        } else if (idx < BLK_OFF) {               // layer1
            int e = idx - L1_OFF;
            v = (e < H) ? b1[e] : w1[e - H];
        } else if (idx < L8_OFF) {                // residual blocks
            int e = idx - BLK_OFF;
            int l = e / BLK_STRIDE, m = e % BLK_STRIDE;
            if      (m < 10)  v = Br1[l * H + m];
            else if (m < 110) v = Wr1[l * H * H + (m - 10)];
            else if (m < 120) v = Br2[l * H + (m - 110)] + Br3[l * H + (m - 110)];
            else if (m < 220) v = Wr2[l * H * H + (m - 120)];
            else              v = Wr3[l * H * H + (m - 220)];
        } else if (idx < L9_OFF) {                // layer8
            int e = idx - L8_OFF;
            v = (e < H) ? b8[e] : w8[e - H];
        } else {                                  // output layer (pad at +1)
            int e = idx - L9_OFF;
            v = (e <= 1) ? b9[0] : w9[e - 2];
        }
        float2 d; d.x = v; d.y = v;
        wp[idx] = d;
    }
}

// ---------------- main kernel: 2 points/thread, LDS-broadcast weights --------
__global__ __launch_bounds__(256, 4) void resnet_fwd(
    const float* __restrict__ x,
    const float2* __restrict__ wp,
    float* __restrict__ out)
{
    __shared__ __align__(16) float2 swp[NENT];

    // stage packed weights into LDS (27.8 KB / WG)
    for (int idx = threadIdx.x; idx < NENT; idx += 256)
        swp[idx] = wp[idx];
    __syncthreads();

    // two duplicated weight-pairs per 16B LDS read
    auto ld4 = [&](int idx) -> v4f { return *(const v4f*)(swp + idx); };

    const int i = blockIdx.x * blockDim.x + threadIdx.x;  // pair index
    const float* xp = x + 6 * (long)i;
    v2f X0; X0.x = xp[0]; X0.y = xp[3];
    v2f X1; X1.x = xp[1]; X1.y = xp[4];
    v2f X2; X2.x = xp[2]; X2.y = xp[5];

    v2f h[H], t1[H], t2[H];

    // ---- layer 0: 3 -> 10, relu ----
#pragma unroll
    for (int j = 0; j < H; ++j) {
        v4f p = ld4(4 * j);       // bias pair | w0 pair
        v4f q = ld4(4 * j + 2);   // w1 pair   | w2 pair
        v2f a = p.xy;
        a = fma2v(X0, p.zw, a);
        a = fma2v(X1, q.xy, a);
        a = fma2v(X2, q.zw, a);
        h[j] = relu2(a);
    }

    // ---- layer 1: 10 -> 10, relu ----
#pragma unroll
    for (int j = 0; j < H; j += 2) {
        v4f b = ld4(L1_OFF + j);
        t1[j] = b.xy; t1[j + 1] = b.zw;
    }
#pragma unroll
    for (int k = 0; k < H; ++k) {
#pragma unroll
        for (int j = 0; j < H; j += 2) {
            v4f w = ld4(L1_OFF + H + k * H + j);
            t1[j]     = fma2v(h[k], w.xy, t1[j]);
            t1[j + 1] = fma2v(h[k], w.zw, t1[j + 1]);
        }
    }
#pragma unroll
    for (int j = 0; j < H; ++j) h[j] = relu2(t1[j]);

    // ---- L residual blocks ----
#pragma unroll 1
    for (int l = 0; l < L; ++l) {
        const int base = BLK_OFF + l * BLK_STRIDE;

        // t1 = relu(h @ W1 + B1)
#pragma unroll
        for (int j = 0; j < H; j += 2) {
            v4f b = ld4(base + j);
            t1[j] = b.xy; t1[j + 1] = b.zw;
        }
#pragma unroll
        for (int k = 0; k < H; ++k) {
#pragma unroll
            for (int j = 0; j < H; j += 2) {
                v4f w = ld4(base + 10 + k * H + j);
                t1[j]     = fma2v(h[k], w.xy, t1[j]);
                t1[j + 1] = fma2v(h[k], w.zw, t1[j + 1]);
            }
        }
#pragma unroll
        for (int j = 0; j < H; ++j) t1[j] = relu2(t1[j]);

        // t2 = (B2+B3) + h @ W2
#pragma unroll
        for (int j = 0; j < H; j += 2) {
            v4f b = ld4(base + 110 + j);
            t2[j] = b.xy; t2[j + 1] = b.zw;
        }
#pragma unroll
        for (int k = 0; k < H; ++k) {
#pragma unroll
            for (int j = 0; j < H; j += 2) {
                v4f w = ld4(base + 120 + k * H + j);
                t2[j]     = fma2v(h[k], w.xy, t2[j]);
                t2[j + 1] = fma2v(h[k], w.zw, t2[j + 1]);
            }
        }

        // t2 += t1 @ W3 ; h = relu(t2)
#pragma unroll
        for (int k = 0; k < H; ++k) {
#pragma unroll
            for (int j = 0; j < H; j += 2) {
                v4f w = ld4(base + 220 + k * H + j);
                t2[j]     = fma2v(t1[k], w.xy, t2[j]);
                t2[j + 1] = fma2v(t1[k], w.zw, t2[j + 1]);
            }
        }
#pragma unroll
        for (int j = 0; j < H; ++j) h[j] = relu2(t2[j]);
    }

    // ---- layer 8: 10 -> 10, relu ----
#pragma unroll
    for (int j = 0; j < H; j += 2) {
        v4f b = ld4(L8_OFF + j);
        t1[j] = b.xy; t1[j + 1] = b.zw;
    }
#pragma unroll
    for (int k = 0; k < H; ++k) {
#pragma unroll
        for (int j = 0; j < H; j += 2) {
            v4f w = ld4(L8_OFF + H + k * H + j);
            t1[j]     = fma2v(h[k], w.xy, t1[j]);
            t1[j + 1] = fma2v(h[k], w.zw, t1[j + 1]);
        }
    }
#pragma unroll
    for (int j = 0; j < H; ++j) h[j] = relu2(t1[j]);

    // ---- output layer: 10 -> 1 ----
    v2f o = tov2(swp[L9_OFF]);
#pragma unroll
    for (int k = 0; k < H; k += 2) {
        v4f w = ld4(L9_OFF + 2 + k);
        o = fma2v(h[k],     w.xy, o);
        o = fma2v(h[k + 1], w.zw, o);
    }

    *(v2f*)(out + 2 * (long)i) = o;
}

extern "C" void kernel_launch(void* const* d_in, const int* in_sizes, int n_in,
                              void* d_out, int out_size, void* d_ws, size_t ws_size,
                              hipStream_t stream)
{
    const float* x   = (const float*)d_in[0];
    const float* w0  = (const float*)d_in[1];
    const float* b0  = (const float*)d_in[2];
    const float* w1  = (const float*)d_in[3];
    const float* b1  = (const float*)d_in[4];
    const float* Wr1 = (const float*)d_in[5];
    const float* Br1 = (const float*)d_in[6];
    const float* Wr2 = (const float*)d_in[7];
    const float* Br2 = (const float*)d_in[8];
    const float* Wr3 = (const float*)d_in[9];
    const float* Br3 = (const float*)d_in[10];
    const float* w8  = (const float*)d_in[11];
    const float* b8  = (const float*)d_in[12];
    const float* w9  = (const float*)d_in[13];
    const float* b9  = (const float*)d_in[14];
    float* out = (float*)d_out;
    float2* wp = (float2*)d_ws;   // 3472 * 8 B = 27.8 KB scratch

    hipLaunchKernelGGL(prepack, dim3(1), dim3(256), 0, stream,
                       w0, b0, w1, b1, Wr1, Br1, Wr2, Br2, Wr3, Br3,
                       w8, b8, w9, b9, wp);

    dim3 block(256);
    dim3 grid(NPTS / 2 / 256);   // 2 points per thread
    hipLaunchKernelGGL(resnet_fwd, grid, block, 0, stream,
                       x, (const float2*)wp, out);
}

// Round 5
// 500.529 us; speedup vs baseline: 1.0081x; 1.0081x over previous
//
#include <hip/hip_runtime.h>

// ResidualNetwork forward, fp32, MI355X (gfx950).
// Round 5: back to SGPR weight delivery (r4's LDS broadcast serialized on the
// per-CU DS pipe: ~1.7k ds_read/wave x 128 waves/CU ~ 473us, theory falsified).
// r1-r3 refit shows ~1 extra VALU op per weight use = compiler materializing
// SGPR weights into VGPRs. Fix: inline asm  v_fmac_f32 vacc, s_w, v_h  with
// "s" constraint -> weight consumed directly from SGPR (legal: 1 scalar read
// per VALU instr). 2 points/thread, scalar accumulators; each weight's SGPR
// feeds both points. Weights prepacked in exact use order (scalar floats) so
// the s_load stream is one monotone walk -> batched s_load_dwordx8/x16.
// VALU stream/wave ~ 12,960 v_fmac + 920 relu + ~460 mov = ~14.4k cyc,
// x32 wave-slots/SIMD ~ 470k cyc ~ 200us target (issue floor 173us).

#define NPTS 4194304
#define H 10
#define L 10

#define L1_OFF 40
#define BLK_OFF 150
#define BLK_STRIDE 320
#define L8_OFF 3350
#define L9_OFF 3460
#define NENT 3471

// acc += w * h, weight pinned to an SGPR (scalar pipe), h/acc in VGPRs.
__device__ __forceinline__ void fmac_s(float& acc, float w, float h) {
    asm("v_fmac_f32 %0, %1, %2" : "+v"(acc) : "s"(w), "v"(h));
}

// ---------------- prepack: weights -> use-order scalar stream ----------------
__global__ __launch_bounds__(256) void prepack(
    const float* __restrict__ w0, const float* __restrict__ b0,
    const float* __restrict__ w1, const float* __restrict__ b1,
    const float* __restrict__ Wr1, const float* __restrict__ Br1,
    const float* __restrict__ Wr2, const float* __restrict__ Br2,
    const float* __restrict__ Wr3, const float* __restrict__ Br3,
    const float* __restrict__ w8, const float* __restrict__ b8,
    const float* __restrict__ w9, const float* __restrict__ b9,
    float* __restrict__ wp)
{
    for (int idx = threadIdx.x; idx < NENT; idx += 256) {
        float v;
        if (idx < L1_OFF) {                       // layer0 per j: b, w0[0][j], w0[1][j], w0[2][j]
            int j = idx >> 2, r = idx & 3;
            v = (r == 0) ? b0[j] : w0[(r - 1) * H + j];
        } else if (idx < BLK_OFF) {               // layer1: b1[10], w1[100]
            int e = idx - L1_OFF;
            v = (e < H) ? b1[e] : w1[e - H];
        } else if (idx < L8_OFF) {                // blocks: B1, W1, B2+B3, W2, W3
            int e = idx - BLK_OFF;
            int l = e / BLK_STRIDE, m = e % BLK_STRIDE;
            if      (m < 10)  v = Br1[l * H + m];
            else if (m < 110) v = Wr1[l * H * H + (m - 10)];
            else if (m < 120) v = Br2[l * H + (m - 110)] + Br3[l * H + (m - 110)];
            else if (m < 220) v = Wr2[l * H * H + (m - 120)];
            else              v = Wr3[l * H * H + (m - 220)];
        } else if (idx < L9_OFF) {                // layer8: b8[10], w8[100]
            int e = idx - L8_OFF;
            v = (e < H) ? b8[e] : w8[e - H];
        } else {                                  // out: b9, w9[10]
            int e = idx - L9_OFF;
            v = (e == 0) ? b9[0] : w9[e - 1];
        }
        wp[idx] = v;
    }
}

// ---------------- main kernel: 2 points/thread, asm-pinned SGPR weights ------
__global__ __launch_bounds__(256, 4) void resnet_fwd(
    const float* __restrict__ x,
    const float* __restrict__ wp,
    float* __restrict__ out)
{
    const int i = blockIdx.x * blockDim.x + threadIdx.x;  // pair index
    const float* xp = x + 6 * (long)i;
    const float xa0 = xp[0], xa1 = xp[1], xa2 = xp[2];
    const float xb0 = xp[3], xb1 = xp[4], xb2 = xp[5];

    float ha[H], hb[H], t1a[H], t1b[H], t2a[H], t2b[H];

    // ---- layer 0: 3 -> 10, relu ----
#pragma unroll
    for (int j = 0; j < H; ++j) {
        float b = wp[4 * j];
        float wx = wp[4 * j + 1], wy = wp[4 * j + 2], wz = wp[4 * j + 3];
        float a = b, c = b;
        fmac_s(a, wx, xa0); fmac_s(c, wx, xb0);
        fmac_s(a, wy, xa1); fmac_s(c, wy, xb1);
        fmac_s(a, wz, xa2); fmac_s(c, wz, xb2);
        ha[j] = fmaxf(a, 0.0f);
        hb[j] = fmaxf(c, 0.0f);
    }

    // ---- layer 1: 10 -> 10, relu ----
#pragma unroll
    for (int j = 0; j < H; ++j) { float b = wp[L1_OFF + j]; t1a[j] = b; t1b[j] = b; }
#pragma unroll
    for (int k = 0; k < H; ++k) {
#pragma unroll
        for (int j = 0; j < H; ++j) {
            float w = wp[L1_OFF + H + k * H + j];
            fmac_s(t1a[j], w, ha[k]);
            fmac_s(t1b[j], w, hb[k]);
        }
    }
#pragma unroll
    for (int j = 0; j < H; ++j) { ha[j] = fmaxf(t1a[j], 0.0f); hb[j] = fmaxf(t1b[j], 0.0f); }

    // ---- L residual blocks ----
#pragma unroll 1
    for (int l = 0; l < L; ++l) {
        const float* __restrict__ wb = wp + BLK_OFF + l * BLK_STRIDE;

        // t1 = relu(h @ W1 + B1)
#pragma unroll
        for (int j = 0; j < H; ++j) { float b = wb[j]; t1a[j] = b; t1b[j] = b; }
#pragma unroll
        for (int k = 0; k < H; ++k) {
#pragma unroll
            for (int j = 0; j < H; ++j) {
                float w = wb[10 + k * H + j];
                fmac_s(t1a[j], w, ha[k]);
                fmac_s(t1b[j], w, hb[k]);
            }
        }
#pragma unroll
        for (int j = 0; j < H; ++j) { t1a[j] = fmaxf(t1a[j], 0.0f); t1b[j] = fmaxf(t1b[j], 0.0f); }

        // t2 = (B2+B3) + h @ W2
#pragma unroll
        for (int j = 0; j < H; ++j) { float b = wb[110 + j]; t2a[j] = b; t2b[j] = b; }
#pragma unroll
        for (int k = 0; k < H; ++k) {
#pragma unroll
            for (int j = 0; j < H; ++j) {
                float w = wb[120 + k * H + j];
                fmac_s(t2a[j], w, ha[k]);
                fmac_s(t2b[j], w, hb[k]);
            }
        }

        // t2 += t1 @ W3 ; h = relu(t2)
#pragma unroll
        for (int k = 0; k < H; ++k) {
#pragma unroll
            for (int j = 0; j < H; ++j) {
                float w = wb[220 + k * H + j];
                fmac_s(t2a[j], w, t1a[k]);
                fmac_s(t2b[j], w, t1b[k]);
            }
        }
#pragma unroll
        for (int j = 0; j < H; ++j) { ha[j] = fmaxf(t2a[j], 0.0f); hb[j] = fmaxf(t2b[j], 0.0f); }
    }

    // ---- layer 8: 10 -> 10, relu ----
#pragma unroll
    for (int j = 0; j < H; ++j) { float b = wp[L8_OFF + j]; t1a[j] = b; t1b[j] = b; }
#pragma unroll
    for (int k = 0; k < H; ++k) {
#pragma unroll
        for (int j = 0; j < H; ++j) {
            float w = wp[L8_OFF + H + k * H + j];
            fmac_s(t1a[j], w, ha[k]);
            fmac_s(t1b[j], w, hb[k]);
        }
    }
#pragma unroll
    for (int j = 0; j < H; ++j) { ha[j] = fmaxf(t1a[j], 0.0f); hb[j] = fmaxf(t1b[j], 0.0f); }

    // ---- output layer: 10 -> 1 ----
    float ob = wp[L9_OFF];
    float oa = ob, oc = ob;
#pragma unroll
    for (int k = 0; k < H; ++k) {
        float w = wp[L9_OFF + 1 + k];
        fmac_s(oa, w, ha[k]);
        fmac_s(oc, w, hb[k]);
    }

    float2 o; o.x = oa; o.y = oc;
    *(float2*)(out + 2 * (long)i) = o;
}

extern "C" void kernel_launch(void* const* d_in, const int* in_sizes, int n_in,
                              void* d_out, int out_size, void* d_ws, size_t ws_size,
                              hipStream_t stream)
{
    const float* x   = (const float*)d_in[0];
    const float* w0  = (const float*)d_in[1];
    const float* b0  = (const float*)d_in[2];
    const float* w1  = (const float*)d_in[3];
    const float* b1  = (const float*)d_in[4];
    const float* Wr1 = (const float*)d_in[5];
    const float* Br1 = (const float*)d_in[6];
    const float* Wr2 = (const float*)d_in[7];
    const float* Br2 = (const float*)d_in[8];
    const float* Wr3 = (const float*)d_in[9];
    const float* Br3 = (const float*)d_in[10];
    const float* w8  = (const float*)d_in[11];
    const float* b8  = (const float*)d_in[12];
    const float* w9  = (const float*)d_in[13];
    const float* b9  = (const float*)d_in[14];
    float* out = (float*)d_out;
    float* wpk = (float*)d_ws;   // 3471 * 4 B = 13.9 KB scratch

    hipLaunchKernelGGL(prepack, dim3(1), dim3(256), 0, stream,
                       w0, b0, w1, b1, Wr1, Br1, Wr2, Br2, Wr3, Br3,
                       w8, b8, w9, b9, wpk);

    dim3 block(256);
    dim3 grid(NPTS / 2 / 256);   // 2 points per thread
    hipLaunchKernelGGL(resnet_fwd, grid, block, 0, stream,
                       x, (const float*)wpk, out);
}

// Round 6
// 345.051 us; speedup vs baseline: 1.4624x; 1.4506x over previous
//
#include <hip/hip_runtime.h>

// ResidualNetwork forward, fp32, MI355X (gfx950).
// Round 6: r3 structure (prepacked duplicated (w,w) float2 stream, compiler
// codegen, v_pk_fma_f32) with 4 points/thread (two point-pairs A,B).
// Validated model: cyc/SIMD = (64/P)(7170P + 6980); the 6980 is per-wave
// weight-materialization cost (1 v_mov_b64 per weight pair) -> amortize by P.
// P=2 -> 284us (r3 measured 280 ok); P=4 -> 238us predicted.
// Each weight pair materialized once, consumed by 2 adjacent pk_fma (A then B).
// r4 lesson: no LDS (DS pipe shared per CU saturates). r5 lesson: no "s"
// pinning (SGPR file ~100 entries -> v_writelane spills on the VALU pipe).
// Stream layout (float2 entries, duplicated (w,w)):
//   [0,40)      layer0 per j: b0[j], w0[0][j], w0[1][j], w0[2][j]
//   [40,150)    layer1: b1[10], w1[100] (k-major)
//   [150,3350)  10 blocks x 320: B1[10], W1[100], (B2+B3)[10], W2[100], W3[100]
//   [3350,3460) layer8: b8[10], w8[100]
//   [3460,3471) out: b9, w9[10]

#define NPTS 4194304
#define H 10
#define L 10

#define L1_OFF 40
#define BLK_OFF 150
#define BLK_STRIDE 320
#define L8_OFF 3350
#define L9_OFF 3460
#define NENT 3471

typedef float v2f __attribute__((ext_vector_type(2)));
typedef float v4f __attribute__((ext_vector_type(4)));

__device__ __forceinline__ v2f tov2(float2 w) { v2f r; r.x = w.x; r.y = w.y; return r; }
__device__ __forceinline__ v2f bc(float s) { v2f r; r.x = s; r.y = s; return r; }
__device__ __forceinline__ v2f fma2v(v2f a, v2f w, v2f c) {
    return __builtin_elementwise_fma(a, w, c);
}
__device__ __forceinline__ v2f relu2(v2f a) {
    return __builtin_elementwise_max(a, bc(0.0f));
}

// ---------------- prepack: weights -> use-order duplicated pairs -------------
__global__ __launch_bounds__(256) void prepack(
    const float* __restrict__ w0, const float* __restrict__ b0,
    const float* __restrict__ w1, const float* __restrict__ b1,
    const float* __restrict__ Wr1, const float* __restrict__ Br1,
    const float* __restrict__ Wr2, const float* __restrict__ Br2,
    const float* __restrict__ Wr3, const float* __restrict__ Br3,
    const float* __restrict__ w8, const float* __restrict__ b8,
    const float* __restrict__ w9, const float* __restrict__ b9,
    float2* __restrict__ wp)
{
    for (int idx = threadIdx.x; idx < NENT; idx += 256) {
        float v;
        if (idx < L1_OFF) {
            int j = idx >> 2, r = idx & 3;
            v = (r == 0) ? b0[j] : w0[(r - 1) * H + j];
        } else if (idx < BLK_OFF) {
            int e = idx - L1_OFF;
            v = (e < H) ? b1[e] : w1[e - H];
        } else if (idx < L8_OFF) {
            int e = idx - BLK_OFF;
            int l = e / BLK_STRIDE, m = e % BLK_STRIDE;
            if      (m < 10)  v = Br1[l * H + m];
            else if (m < 110) v = Wr1[l * H * H + (m - 10)];
            else if (m < 120) v = Br2[l * H + (m - 110)] + Br3[l * H + (m - 110)];
            else if (m < 220) v = Wr2[l * H * H + (m - 120)];
            else              v = Wr3[l * H * H + (m - 220)];
        } else if (idx < L9_OFF) {
            int e = idx - L8_OFF;
            v = (e < H) ? b8[e] : w8[e - H];
        } else {
            int e = idx - L9_OFF;
            v = (e == 0) ? b9[0] : w9[e - 1];
        }
        float2 d; d.x = v; d.y = v;
        wp[idx] = d;
    }
}

// ---------------- main kernel: 4 points/thread (2 pk-pairs) ------------------
__global__ __launch_bounds__(256, 3) void resnet_fwd(
    const float* __restrict__ x,
    const float2* __restrict__ wp,
    float* __restrict__ out)
{
    const long i = (long)blockIdx.x * blockDim.x + threadIdx.x;  // quad index
    const float* xp = x + 12 * i;
    // pair A = points (4i, 4i+1), pair B = (4i+2, 4i+3)
    v2f XA0, XA1, XA2, XB0, XB1, XB2;
    XA0.x = xp[0]; XA0.y = xp[3];  XB0.x = xp[6]; XB0.y = xp[9];
    XA1.x = xp[1]; XA1.y = xp[4];  XB1.x = xp[7]; XB1.y = xp[10];
    XA2.x = xp[2]; XA2.y = xp[5];  XB2.x = xp[8]; XB2.y = xp[11];

    v2f hA[H], hB[H], t1A[H], t1B[H], t2A[H], t2B[H];

    // ---- layer 0: 3 -> 10, relu ----
#pragma unroll
    for (int j = 0; j < H; ++j) {
        v2f b  = tov2(wp[4 * j]);
        v2f wx = tov2(wp[4 * j + 1]);
        v2f wy = tov2(wp[4 * j + 2]);
        v2f wz = tov2(wp[4 * j + 3]);
        v2f a = b, c = b;
        a = fma2v(XA0, wx, a);  c = fma2v(XB0, wx, c);
        a = fma2v(XA1, wy, a);  c = fma2v(XB1, wy, c);
        a = fma2v(XA2, wz, a);  c = fma2v(XB2, wz, c);
        hA[j] = relu2(a);
        hB[j] = relu2(c);
    }

    // ---- layer 1: 10 -> 10, relu ----
#pragma unroll
    for (int j = 0; j < H; ++j) {
        v2f b = tov2(wp[L1_OFF + j]);
        t1A[j] = b; t1B[j] = b;
    }
#pragma unroll
    for (int k = 0; k < H; ++k) {
#pragma unroll
        for (int j = 0; j < H; ++j) {
            v2f w = tov2(wp[L1_OFF + H + k * H + j]);
            t1A[j] = fma2v(hA[k], w, t1A[j]);
            t1B[j] = fma2v(hB[k], w, t1B[j]);
        }
    }
#pragma unroll
    for (int j = 0; j < H; ++j) { hA[j] = relu2(t1A[j]); hB[j] = relu2(t1B[j]); }

    // ---- L residual blocks ----
#pragma unroll 1
    for (int l = 0; l < L; ++l) {
        const float2* __restrict__ wb = wp + BLK_OFF + l * BLK_STRIDE;

        // t1 = relu(h @ W1 + B1)
#pragma unroll
        for (int j = 0; j < H; ++j) {
            v2f b = tov2(wb[j]);
            t1A[j] = b; t1B[j] = b;
        }
#pragma unroll
        for (int k = 0; k < H; ++k) {
#pragma unroll
            for (int j = 0; j < H; ++j) {
                v2f w = tov2(wb[10 + k * H + j]);
                t1A[j] = fma2v(hA[k], w, t1A[j]);
                t1B[j] = fma2v(hB[k], w, t1B[j]);
            }
        }
#pragma unroll
        for (int j = 0; j < H; ++j) { t1A[j] = relu2(t1A[j]); t1B[j] = relu2(t1B[j]); }

        // t2 = (B2+B3) + h @ W2   (h dies after this)
#pragma unroll
        for (int j = 0; j < H; ++j) {
            v2f b = tov2(wb[110 + j]);
            t2A[j] = b; t2B[j] = b;
        }
#pragma unroll
        for (int k = 0; k < H; ++k) {
#pragma unroll
            for (int j = 0; j < H; ++j) {
                v2f w = tov2(wb[120 + k * H + j]);
                t2A[j] = fma2v(hA[k], w, t2A[j]);
                t2B[j] = fma2v(hB[k], w, t2B[j]);
            }
        }

        // t2 += t1 @ W3 ; h = relu(t2)
#pragma unroll
        for (int k = 0; k < H; ++k) {
#pragma unroll
            for (int j = 0; j < H; ++j) {
                v2f w = tov2(wb[220 + k * H + j]);
                t2A[j] = fma2v(t1A[k], w, t2A[j]);
                t2B[j] = fma2v(t1B[k], w, t2B[j]);
            }
        }
#pragma unroll
        for (int j = 0; j < H; ++j) { hA[j] = relu2(t2A[j]); hB[j] = relu2(t2B[j]); }
    }

    // ---- layer 8: 10 -> 10, relu ----
#pragma unroll
    for (int j = 0; j < H; ++j) {
        v2f b = tov2(wp[L8_OFF + j]);
        t1A[j] = b; t1B[j] = b;
    }
#pragma unroll
    for (int k = 0; k < H; ++k) {
#pragma unroll
        for (int j = 0; j < H; ++j) {
            v2f w = tov2(wp[L8_OFF + H + k * H + j]);
            t1A[j] = fma2v(hA[k], w, t1A[j]);
            t1B[j] = fma2v(hB[k], w, t1B[j]);
        }
    }
#pragma unroll
    for (int j = 0; j < H; ++j) { hA[j] = relu2(t1A[j]); hB[j] = relu2(t1B[j]); }

    // ---- output layer: 10 -> 1 ----
    v2f ob = tov2(wp[L9_OFF]);
    v2f oA = ob, oB = ob;
#pragma unroll
    for (int k = 0; k < H; ++k) {
        v2f w = tov2(wp[L9_OFF + 1 + k]);
        oA = fma2v(hA[k], w, oA);
        oB = fma2v(hB[k], w, oB);
    }

    // 4 consecutive outputs -> one dwordx4 store
    v4f o; o.x = oA.x; o.y = oA.y; o.z = oB.x; o.w = oB.y;
    *(v4f*)(out + 4 * i) = o;
}

extern "C" void kernel_launch(void* const* d_in, const int* in_sizes, int n_in,
                              void* d_out, int out_size, void* d_ws, size_t ws_size,
                              hipStream_t stream)
{
    const float* x   = (const float*)d_in[0];
    const float* w0  = (const float*)d_in[1];
    const float* b0  = (const float*)d_in[2];
    const float* w1  = (const float*)d_in[3];
    const float* b1  = (const float*)d_in[4];
    const float* Wr1 = (const float*)d_in[5];
    const float* Br1 = (const float*)d_in[6];
    const float* Wr2 = (const float*)d_in[7];
    const float* Br2 = (const float*)d_in[8];
    const float* Wr3 = (const float*)d_in[9];
    const float* Br3 = (const float*)d_in[10];
    const float* w8  = (const float*)d_in[11];
    const float* b8  = (const float*)d_in[12];
    const float* w9  = (const float*)d_in[13];
    const float* b9  = (const float*)d_in[14];
    float* out = (float*)d_out;
    float2* wp = (float2*)d_ws;   // 3471 * 8 B = 27.8 KB scratch

    hipLaunchKernelGGL(prepack, dim3(1), dim3(256), 0, stream,
                       w0, b0, w1, b1, Wr1, Br1, Wr2, Br2, Wr3, Br3,
                       w8, b8, w9, b9, wp);

    dim3 block(256);
    dim3 grid(NPTS / 4 / 256);   // 4 points per thread
    hipLaunchKernelGGL(resnet_fwd, grid, block, 0, stream,
                       x, (const float2*)wp, out);
}